// Round 1
// baseline (72.241 us; speedup 1.0000x reference)
//
#include <hip/hip_runtime.h>

#define N_BOXES 4194304
#define BCE_COEFF 0.2f

__device__ __forceinline__ float sigmoidf_fast(float x) {
    return 1.0f / (1.0f + __expf(-x));
}

__global__ __launch_bounds__(256) void eiou_bce_kernel(
        const float* __restrict__ preds,
        const float* __restrict__ target,
        float* __restrict__ out) {
    // Each thread handles 4 boxes = 20 floats = 5 float4 per input.
    // Base byte offset = tid * 80 -> 16B aligned.
    const int tid = blockIdx.x * blockDim.x + threadIdx.x;
    const float4* p4 = reinterpret_cast<const float4*>(preds) + (size_t)tid * 5;
    const float4* t4 = reinterpret_cast<const float4*>(target) + (size_t)tid * 5;

    float4 pa = p4[0], pb = p4[1], pc = p4[2], pd = p4[3], pe = p4[4];
    float4 ua = t4[0], ub = t4[1], uc = t4[2], ud = t4[3], ue = t4[4];

    const float P[20] = {pa.x, pa.y, pa.z, pa.w,
                         pb.x, pb.y, pb.z, pb.w,
                         pc.x, pc.y, pc.z, pc.w,
                         pd.x, pd.y, pd.z, pd.w,
                         pe.x, pe.y, pe.z, pe.w};
    const float T[20] = {ua.x, ua.y, ua.z, ua.w,
                         ub.x, ub.y, ub.z, ub.w,
                         uc.x, uc.y, uc.z, uc.w,
                         ud.x, ud.y, ud.z, ud.w,
                         ue.x, ue.y, ue.z, ue.w};

    float acc = 0.0f;
#pragma unroll
    for (int b = 0; b < 4; ++b) {
        const float x  = P[5 * b + 0];
        const float y  = T[5 * b + 0];
        const float p0 = sigmoidf_fast(P[5 * b + 1]);
        const float p1 = sigmoidf_fast(P[5 * b + 2]);
        const float p2 = sigmoidf_fast(P[5 * b + 3]);
        const float p3 = sigmoidf_fast(P[5 * b + 4]);
        const float t0 = T[5 * b + 1];
        const float t1 = T[5 * b + 2];
        const float t2 = T[5 * b + 3];
        const float t3 = T[5 * b + 4];

        // ---- EIoU (replicates reference exactly, incl. overlap<0 clamp) ----
        const float pred_area   = fabsf(p2 - p0) * fabsf(p3 - p1);
        const float target_area = (t2 - t0) * (t3 - t1);

        const float xp1 = fminf(p2, p0), xp2 = fmaxf(p2, p0);
        const float yp1 = fminf(p1, p3), yp2 = fmaxf(p1, p3);

        const float x1 = fmaxf(xp1, t0), x2 = fminf(xp2, t2);
        const float y1 = fmaxf(yp1, t1), y2 = fminf(yp2, t3);

        float ov = (x2 - x1) * (y2 - y1);
        ov = (ov < 0.0f) ? 0.0f : ov;

        const float x1c = fminf(xp1, t0), x2c = fmaxf(xp2, t2);
        const float y1c = fminf(yp1, t1), y2c = fmaxf(yp2, t3);

        const float cw = x2c - x1c, ch = y2c - y1c;
        const float w  = xp2 - xp1, wt = t2 - t0;
        const float h  = yp2 - yp1, ht = t3 - t1;

        const float iou = ov / (target_area + pred_area - ov);

        const float cpx = (xp2 + xp1) * 0.5f, cpy = (yp2 + yp1) * 0.5f;
        const float ctx = (t2 + t0) * 0.5f,   cty = (t3 + t1) * 0.5f;
        const float diag = cw * cw + ch * ch;
        const float dx = cpx - ctx, dy = cpy - cty;

        const float center_part = (dx * dx + dy * dy) / diag;
        const float dwv = w - wt;
        const float width_part  = (dwv * dwv) / (cw * cw);
        const float dhv = h - ht;
        const float height_part = (dhv * dhv) / (ht * ht);

        const float eiou = 1.0f - (iou - (center_part + width_part + height_part));

        // ---- BCE-with-logits ----
        const float bce = fmaxf(x, 0.0f) - x * y + log1pf(__expf(-fabsf(x)));

        acc += BCE_COEFF * bce + eiou;
    }

    // ---- wave-64 reduction ----
#pragma unroll
    for (int off = 32; off > 0; off >>= 1)
        acc += __shfl_down(acc, off);

    __shared__ float wave_sums[4];
    const int lane = threadIdx.x & 63;
    const int wid  = threadIdx.x >> 6;
    if (lane == 0) wave_sums[wid] = acc;
    __syncthreads();

    if (threadIdx.x == 0) {
        const float s = wave_sums[0] + wave_sums[1] + wave_sums[2] + wave_sums[3];
        atomicAdd(out, s * (1.0f / (float)N_BOXES));
    }
}

extern "C" void kernel_launch(void* const* d_in, const int* in_sizes, int n_in,
                              void* d_out, int out_size, void* d_ws, size_t ws_size,
                              hipStream_t stream) {
    const float* preds  = (const float*)d_in[0];
    const float* target = (const float*)d_in[1];
    float* out = (float*)d_out;

    // d_out is poisoned (0xAA) before timing and never re-poisoned between
    // replays -> zero it ourselves every call (graph-capture safe).
    hipMemsetAsync(out, 0, sizeof(float), stream);

    // 4 boxes per thread: 4194304 / 4 / 256 = 4096 blocks exactly.
    const int threads = 256;
    const int blocks  = N_BOXES / 4 / threads;
    eiou_bce_kernel<<<blocks, threads, 0, stream>>>(preds, target, out);
}

// Round 2
// 41.996 us; speedup vs baseline: 1.7202x; 1.7202x over previous
//
#include <hip/hip_runtime.h>

#define N_BOXES 4194304
#define BCE_COEFF 0.2f
#define BLOCK 256
#define CHUNK_BOXES 1024                      // boxes staged per chunk
#define CHUNKS 4                              // chunks per block
#define BOXES_PER_BLOCK (CHUNK_BOXES * CHUNKS)

__global__ __launch_bounds__(BLOCK) void eiou_bce_kernel(
        const float* __restrict__ preds,
        const float* __restrict__ target,
        float* __restrict__ out) {
    // 1024 boxes * 5 floats = 5120 floats = 20 KB per input. 40 KB total LDS.
    __shared__ float sp[CHUNK_BOXES * 5];
    __shared__ float st[CHUNK_BOXES * 5];

    const int t = threadIdx.x;
    const size_t blockBase = (size_t)blockIdx.x * BOXES_PER_BLOCK;

    float acc = 0.0f;

    for (int c = 0; c < CHUNKS; ++c) {
        const size_t chunkBase = blockBase + (size_t)c * CHUNK_BOXES;   // boxes
        // 20*chunkBase bytes, chunkBase multiple of 1024 -> 16B aligned.
        const float4* p4 = reinterpret_cast<const float4*>(preds + chunkBase * 5);
        const float4* t4 = reinterpret_cast<const float4*>(target + chunkBase * 5);
        float4* sp4 = reinterpret_cast<float4*>(sp);
        float4* st4 = reinterpret_cast<float4*>(st);

        if (c) __syncthreads();   // previous chunk's LDS reads complete

        // Fully coalesced staging: lane i reads float4 index (i + k*256)
        // -> consecutive 16B across the wave, 16 cache lines / instruction.
#pragma unroll
        for (int k = 0; k < 5; ++k) {
            sp4[t + k * BLOCK] = p4[t + k * BLOCK];
            st4[t + k * BLOCK] = t4[t + k * BLOCK];
        }
        __syncthreads();

        // Each thread handles boxes t, t+256, t+512, t+768 of this chunk.
        // LDS read addr = 5*b + j, lanes stride 5 (odd) -> 2 lanes/bank, free.
#pragma unroll
        for (int k = 0; k < 4; ++k) {
            const int b = t + k * BLOCK;
            const float* __restrict__ P = &sp[b * 5];
            const float* __restrict__ T = &st[b * 5];

            const float x = P[0];
            const float y = T[0];
            const float p0 = __fdividef(1.0f, 1.0f + __expf(-P[1]));
            const float p1 = __fdividef(1.0f, 1.0f + __expf(-P[2]));
            const float p2 = __fdividef(1.0f, 1.0f + __expf(-P[3]));
            const float p3 = __fdividef(1.0f, 1.0f + __expf(-P[4]));
            const float t0 = T[1], t1 = T[2], t2 = T[3], t3 = T[4];

            // ---- EIoU (reference-exact dataflow, fast-math ops) ----
            const float pred_area   = fabsf(p2 - p0) * fabsf(p3 - p1);
            const float target_area = (t2 - t0) * (t3 - t1);

            const float xp1 = fminf(p2, p0), xp2 = fmaxf(p2, p0);
            const float yp1 = fminf(p1, p3), yp2 = fmaxf(p1, p3);

            const float x1 = fmaxf(xp1, t0), x2 = fminf(xp2, t2);
            const float y1 = fmaxf(yp1, t1), y2 = fminf(yp2, t3);

            float ov = (x2 - x1) * (y2 - y1);
            ov = (ov < 0.0f) ? 0.0f : ov;

            const float x1c = fminf(xp1, t0), x2c = fmaxf(xp2, t2);
            const float y1c = fminf(yp1, t1), y2c = fmaxf(yp2, t3);

            const float cw = x2c - x1c, ch = y2c - y1c;
            const float w  = xp2 - xp1, wt = t2 - t0;
            const float h  = yp2 - yp1, ht = t3 - t1;

            const float iou = __fdividef(ov, target_area + pred_area - ov);

            const float cpx = (xp2 + xp1) * 0.5f, cpy = (yp2 + yp1) * 0.5f;
            const float ctx = (t2 + t0) * 0.5f,   cty = (t3 + t1) * 0.5f;
            const float diag = cw * cw + ch * ch;
            const float dx = cpx - ctx, dy = cpy - cty;

            const float center_part = __fdividef(dx * dx + dy * dy, diag);
            const float dwv = w - wt;
            const float width_part  = __fdividef(dwv * dwv, cw * cw);
            const float dhv = h - ht;
            const float height_part = __fdividef(dhv * dhv, ht * ht);

            const float eiou = 1.0f - (iou - (center_part + width_part + height_part));

            // ---- BCE-with-logits (fast log/exp; arg of log in (1,2]) ----
            const float bce = fmaxf(x, 0.0f) - x * y
                            + __logf(1.0f + __expf(-fabsf(x)));

            acc += BCE_COEFF * bce + eiou;
        }
    }

    // ---- wave-64 reduction ----
#pragma unroll
    for (int off = 32; off > 0; off >>= 1)
        acc += __shfl_down(acc, off);

    __syncthreads();              // all LDS compute reads done; reuse sp
    if ((t & 63) == 0) sp[t >> 6] = acc;
    __syncthreads();
    if (t == 0) {
        const float s = sp[0] + sp[1] + sp[2] + sp[3];
        atomicAdd(out, s * (1.0f / (float)N_BOXES));
    }
}

extern "C" void kernel_launch(void* const* d_in, const int* in_sizes, int n_in,
                              void* d_out, int out_size, void* d_ws, size_t ws_size,
                              hipStream_t stream) {
    const float* preds  = (const float*)d_in[0];
    const float* target = (const float*)d_in[1];
    float* out = (float*)d_out;

    // d_out is poisoned once before timing; zero it every call.
    hipMemsetAsync(out, 0, sizeof(float), stream);

    const int blocks = N_BOXES / BOXES_PER_BLOCK;   // 1024 blocks, 4/CU
    eiou_bce_kernel<<<blocks, BLOCK, 0, stream>>>(preds, target, out);
}